// Round 11
// baseline (282.036 us; speedup 1.0000x reference)
//
#include <hip/hip_runtime.h>
#include <stdint.h>

typedef unsigned short u16;
typedef float f32x4 __attribute__((ext_vector_type(4)));
typedef short s16x8 __attribute__((ext_vector_type(8)));

#define DEV __device__ __forceinline__

DEV float b2f(u16 u){ union{unsigned i; float f;} v; v.i = ((unsigned)u)<<16; return v.f; }
DEV u16 f2b(float f){ union{float f; unsigned i;} v; v.f=f; unsigned u=v.i;
                      return (u16)((u + 0x7FFFu + ((u>>16)&1u))>>16); }
DEV s16x8 ld8(const u16* p){ return *(const s16x8*)p; }

#define MFMA(d,a,b) d = __builtin_amdgcn_mfma_f32_16x16x32_bf16(a, b, d, 0, 0, 0)

// async 16B global->LDS (wave-uniform LDS base + lane*16 by construction)
DEV void gload16(const u16* g, u16* l){
  __builtin_amdgcn_global_load_lds((const __attribute__((address_space(1))) void*)g,
                                   (__attribute__((address_space(3))) void*)l, 16, 0, 0);
}

// quadrant map: group g, local l -> x row index
DEV int qmapf(int g, int l){
  int h2 = l/27, w2 = l - h2*27;
  return (g>>1)*810 + h2*54 + (g&1)*27 + w2;
}

// ---------------- dtype detection: f32 misread as bf16 has wild exponents ---
__global__ __launch_bounds__(64) void detect_kernel(const u16* __restrict__ x, int* flag){
  int lane = threadIdx.x;
  int cnt = 0;
  for (int i=0;i<32;i++){
    u16 v = x[lane*32+i];
    int e = (v >> 7) & 0xFF;
    if (e >= 0xE0) cnt++;           // |val| >= 2^97: impossible for N(0,1) bf16 data
  }
  for (int off=1; off<64; off<<=1) cnt += __shfl_xor(cnt, off, 64);
  if (lane==0) *flag = (cnt >= 16) ? 1 : 0;   // 1 = device buffers are f32
}

// ---------------- canonicalize small tensors to contiguous bf16 -------------
struct NormArgs { const void* src[15]; int cumblk[16]; };

__global__ __launch_bounds__(64) void norm_kernel(NormArgs a, const int* __restrict__ flag,
                                                  u16* __restrict__ canon){
  int b = blockIdx.x, lane = threadIdx.x;
  int t = 0;
  while (t < 14 && b >= a.cumblk[t+1]) t++;
  int off = (b - a.cumblk[t])*512 + lane*8;
  size_t g = (size_t)b*512 + lane*8;
  if (*flag){
    const float* s = (const float*)a.src[t] + off;
    s16x8 o;
#pragma unroll
    for (int j=0;j<8;j++) o[j] = (short)f2b(s[j]);
    *(s16x8*)(canon+g) = o;
  } else {
    *(s16x8*)(canon+g) = *(const s16x8*)((const u16*)a.src[t] + off);
  }
}

// ---------------- batched tiled transpose (dtype-aware + row-mapped) --------
struct TJobs {
  const void* src[8]; u16* dst[8];
  int R[8], C32[8], srcld[8], dstld[8], gmap[8];
  int cum[9];
};
__global__ void trans_kernel(TJobs J, const int* __restrict__ flag){
  int b = blockIdx.x;
  int t = 0;
  while (b >= J.cum[t+1]) t++;
  int idx = b - J.cum[t];
  int tr = idx / J.C32[t], tc = idx - tr*J.C32[t];
  int r0 = tr*32, c0 = tc*32;
  const void* src = J.src[t];
  u16* dst = J.dst[t];
  int R = J.R[t], srcld = J.srcld[t], dstld = J.dstld[t], g = J.gmap[t];
  int isf32 = flag ? *flag : 0;
  __shared__ u16 tile[32][33];
  int tx = threadIdx.x, ty = threadIdx.y;   // (32,8)
#pragma unroll
  for (int i=0;i<4;i++){
    int r = r0 + ty + i*8, c = c0 + tx;
    u16 v = 0;
    if (r < R){
      int sr = (g >= 0) ? qmapf(g, r) : r;
      size_t si = (size_t)sr*srcld + c;
      v = isf32 ? f2b(((const float*)src)[si]) : ((const u16*)src)[si];
    }
    tile[ty+i*8][tx] = v;
  }
  __syncthreads();
#pragma unroll
  for (int i=0;i<4;i++){
    int c = c0 + ty + i*8, r = r0 + tx;
    if (r < dstld) dst[(size_t)c*dstld + r] = tile[tx][ty+i*8];
  }
}

// ---------------- LDS-staged MFMA GEMM: C = A(MxK) @ BT(NxK)^T --------------
__global__ __launch_bounds__(256) void gemm_s_kernel(
    const u16* __restrict__ A, const u16* __restrict__ BT,
    const u16* __restrict__ bias, const u16* __restrict__ bias2, const u16* __restrict__ bias3,
    int M, int N, int K, int KS, float* __restrict__ pout,
    const u16* __restrict__ resid_bf, const float* __restrict__ resid_f,
    u16* __restrict__ out_bf, float* __restrict__ out_f,
    const int* __restrict__ flagp, u16* __restrict__ dev_bf, float* __restrict__ dev_f,
    int relu)
{
  __shared__ u16 Al[2][64*64];
  __shared__ u16 Bl[2][64*64];
  int tid = threadIdx.x, lane = tid & 63, w = tid >> 6;
  int lr = lane & 15, lk = lane >> 4;
  int wr = w >> 1, wc = w & 1;
  int rowBase = blockIdx.y*64, colBase = blockIdx.x*64;
  int z = blockIdx.z;
  int kStep = K / KS;
  int kOff = kStep * z;
  int nk = kStep >> 6;

  f32x4 acc[2][2] = {{{0,0,0,0},{0,0,0,0}},{{0,0,0,0},{0,0,0,0}}};

  auto STAGE = [&](int buf, int kt){
    int kb = kOff + kt*64;
#pragma unroll
    for (int it=0; it<2; ++it){
      int ch  = it*256 + tid;
      int row = ch >> 3, seg = ch & 7;
      int sseg = (seg ^ (row & 7)) << 3;
      int ar = min(rowBase + row, M-1);
      gload16(A  + (size_t)ar*K + kb + sseg, Al[buf] + ch*8);
      int bc = colBase + row;
      gload16(BT + (size_t)bc*K + kb + sseg, Bl[buf] + ch*8);
    }
  };

  STAGE(0, 0);
  asm volatile("s_waitcnt vmcnt(0)" ::: "memory");
  __syncthreads();
  int cur = 0;
  for (int kt=0; kt<nk; ++kt){
    if (kt+1 < nk) STAGE(cur^1, kt+1);
#pragma unroll
    for (int ks=0; ks<2; ++ks){
      s16x8 af[2], bf[2];
#pragma unroll
      for (int m=0;m<2;m++){
        int ar = wr*32 + m*16 + lr;
        af[m] = *(const s16x8*)(Al[cur] + ar*64 + ((((ks<<2)+lk) ^ (ar&7))<<3));
        int bc = wc*32 + m*16 + lr;
        bf[m] = *(const s16x8*)(Bl[cur] + bc*64 + ((((ks<<2)+lk) ^ (bc&7))<<3));
      }
#pragma unroll
      for (int m=0;m<2;m++)
#pragma unroll
        for (int n=0;n<2;n++) MFMA(acc[m][n], af[m], bf[n]);
    }
    asm volatile("s_waitcnt vmcnt(0)" ::: "memory");
    __syncthreads();
    cur ^= 1;
  }

  if (pout){
    float* pz = pout + (size_t)z*M*N;
#pragma unroll
    for (int m=0;m<2;m++)
#pragma unroll
      for (int n=0;n<2;n++){
        int col = colBase + wc*32 + n*16 + lr;
#pragma unroll
        for (int r=0;r<4;r++){
          int row = rowBase + wr*32 + m*16 + lk*4 + r;
          if (row < M) pz[(size_t)row*N + col] = acc[m][n][r];
        }
      }
    return;
  }
  int isf32 = flagp ? *flagp : 0;
#pragma unroll
  for (int m=0;m<2;m++){
#pragma unroll
    for (int n=0;n<2;n++){
      int col = colBase + wc*32 + n*16 + lr;
      float bv = 0.f;
      if (bias){
        if (bias2){
          const u16* bp = (col < 512) ? bias : ((col < 1024) ? bias2 : bias3);
          bv = b2f(bp[col & 511]);
        } else bv = b2f(bias[col]);
      }
#pragma unroll
      for (int r=0;r<4;r++){
        int row = rowBase + wr*32 + m*16 + lk*4 + r;
        if (row < M){
          float v = acc[m][n][r] + bv;
          if (relu) v = fmaxf(v, 0.f);
          size_t idx = (size_t)row*N + col;
          if (resid_bf) v += b2f(resid_bf[idx]);
          if (resid_f)  v += resid_f[idx];
          if (out_f)  out_f[idx]  = v;
          if (out_bf) out_bf[idx] = f2b(v);
          if (flagp){ if (isf32) dev_f[idx] = v; else dev_bf[idx] = f2b(v); }
        }
      }
    }
  }
}

// ---------------- split-K combine + epilogue (N=512) ------------------------
__global__ __launch_bounds__(256) void gemm_comb_kernel(
    const float* __restrict__ pout, int KS, const u16* __restrict__ bias,
    int M, int relu,
    const u16* __restrict__ resid_bf, const float* __restrict__ resid_f,
    u16* __restrict__ out_bf, float* __restrict__ out_f,
    const int* __restrict__ flagp, u16* __restrict__ dev_bf, float* __restrict__ dev_f)
{
  int w = threadIdx.x >> 6, lane = threadIdx.x & 63;
  int row = blockIdx.x*4 + w;
  if (row >= M) return;
  int c0 = lane*8;
  float acc[8];
  const float* p0 = pout + (size_t)row*512 + c0;
#pragma unroll
  for (int j=0;j<8;j++) acc[j] = p0[j];
  for (int z=1; z<KS; ++z){
    const float* pz = pout + ((size_t)z*M + row)*512 + c0;
#pragma unroll
    for (int j=0;j<8;j++) acc[j] += pz[j];
  }
  int isf32 = flagp ? *flagp : 0;
#pragma unroll
  for (int j=0;j<8;j++){
    int col = c0 + j;
    float v = acc[j] + (bias ? b2f(bias[col]) : 0.f);
    if (relu) v = fmaxf(v, 0.f);
    size_t idx = (size_t)row*512 + col;
    if (resid_bf) v += b2f(resid_bf[idx]);
    if (resid_f)  v += resid_f[idx];
    if (out_f)  out_f[idx]  = v;
    if (out_bf) out_bf[idx] = f2b(v);
    if (flagp){ if (isf32) dev_f[idx] = v; else dev_bf[idx] = f2b(v); }
  }
}

// ---------------- split-K combine + residual + LayerNorm (fused, O-proj) ----
__global__ __launch_bounds__(256) void comb_ln_kernel(
    const float* __restrict__ pout, int KS, const u16* __restrict__ bias, int M,
    const u16* __restrict__ resid_bf,
    float* __restrict__ out_f,
    const u16* __restrict__ gw, const u16* __restrict__ bw,
    u16* __restrict__ out_ln)
{
  int w = threadIdx.x >> 6, lane = threadIdx.x & 63;
  int row = blockIdx.x*4 + w;
  if (row >= M) return;
  int c0 = lane*8;
  float acc[8];
  const float* p0 = pout + (size_t)row*512 + c0;
#pragma unroll
  for (int j=0;j<8;j++) acc[j] = p0[j];
  for (int z=1; z<KS; ++z){
    const float* pz = pout + ((size_t)z*M + row)*512 + c0;
#pragma unroll
    for (int j=0;j<8;j++) acc[j] += pz[j];
  }
  float s = 0.f;
#pragma unroll
  for (int j=0;j<8;j++){
    acc[j] += b2f(bias[c0+j]) + b2f(resid_bf[(size_t)row*512 + c0 + j]);
    out_f[(size_t)row*512 + c0 + j] = acc[j];
    s += acc[j];
  }
#pragma unroll
  for (int off=1; off<64; off<<=1) s += __shfl_xor(s, off, 64);
  float mean = s*(1.f/512.f);
  float vs = 0.f;
#pragma unroll
  for (int j=0;j<8;j++){ float d = acc[j]-mean; vs += d*d; }
#pragma unroll
  for (int off=1; off<64; off<<=1) vs += __shfl_xor(vs, off, 64);
  float rstd = 1.f/sqrtf(vs*(1.f/512.f) + 1e-5f);
#pragma unroll
  for (int j=0;j<8;j++){
    int c = c0+j;
    out_ln[(size_t)row*512 + c] = f2b((acc[j]-mean)*rstd*b2f(gw[c]) + b2f(bw[c]));
  }
}

// ---------------- FFN2s-combine + mem_fin[1] + temporal-combine + LN --------
// xa = comb(po,2)+bias+xu -> dev out; xut = xa + mean_g ot; yt = LN(xut)
__global__ __launch_bounds__(256) void ffn2_comb_ln_kernel(
    const float* __restrict__ pout, const u16* __restrict__ bias, int M,
    const float* __restrict__ xu, const float* __restrict__ ot,
    const int* __restrict__ flagp, u16* __restrict__ dev_bf, float* __restrict__ dev_f,
    float* __restrict__ xut, const u16* __restrict__ gw, const u16* __restrict__ bw,
    u16* __restrict__ out_ln)
{
  int w = threadIdx.x >> 6, lane = threadIdx.x & 63;
  int row = blockIdx.x*4 + w;
  if (row >= M) return;
  int c0 = lane*8, l = row % 405;
  int isf32 = *flagp;
  const float* p0 = pout + (size_t)row*512 + c0;
  const float* p1 = pout + ((size_t)M + row)*512 + c0;
  const float* px = xu + (size_t)row*512 + c0;
  float xv[8];
  float s = 0.f;
#pragma unroll
  for (int j=0;j<8;j++){
    float v = p0[j] + p1[j] + b2f(bias[c0+j]) + px[j];     // xa0
    size_t idx = (size_t)row*512 + c0 + j;
    if (isf32) dev_f[idx] = v; else dev_bf[idx] = f2b(v);
    float t = v + 0.25f*( ot[((size_t)l      )*512 + c0 + j]
                        + ot[((size_t)(405+l) )*512 + c0 + j]
                        + ot[((size_t)(810+l) )*512 + c0 + j]
                        + ot[((size_t)(1215+l))*512 + c0 + j]);
    xut[idx] = t;
    xv[j] = t; s += t;
  }
#pragma unroll
  for (int off=1; off<64; off<<=1) s += __shfl_xor(s, off, 64);
  float mean = s*(1.f/512.f);
  float vs = 0.f;
#pragma unroll
  for (int j=0;j<8;j++){ float d = xv[j]-mean; vs += d*d; }
#pragma unroll
  for (int off=1; off<64; off<<=1) vs += __shfl_xor(vs, off, 64);
  float rstd = 1.f/sqrtf(vs*(1.f/512.f) + 1e-5f);
#pragma unroll
  for (int j=0;j<8;j++){
    int c = c0+j;
    out_ln[(size_t)row*512 + c] = f2b((xv[j]-mean)*rstd*b2f(gw[c]) + b2f(bw[c]));
  }
}

// ---------------- flash partial, 4 waves/block, gload_lds-staged K/V --------
// usemap: Q/K row indices mapped via qmapf(uh, row) into the flat x tensor.
__global__ __launch_bounds__(256) void flash4_kernel(
    const u16* __restrict__ Qp, const u16* __restrict__ Kp, const u16* __restrict__ VTp,
    float* __restrict__ po, float* __restrict__ pm, float* __restrict__ pl,
    int M, int Nk, int qld, int tiles_total, int nchunks,
    long q_hi_stride, long vt_hi_stride, int vt_ld, float scale, int usemap)
{
  int u = blockIdx.y, c = blockIdx.z;
  int uh = u >> 2, ul = u & 3;
  const u16* q  = Qp  + (size_t)uh*q_hi_stride + ul*128;
  const u16* kk = Kp  + (size_t)uh*q_hi_stride + ul*128;
  const u16* vt = VTp + (size_t)uh*vt_hi_stride + (size_t)(ul*128)*vt_ld;
  int tid = threadIdx.x, lane = tid & 63, w = tid >> 6;
  int lr = lane & 15, lk = lane >> 4;
  int r0 = blockIdx.x*64 + w*16;
  int qr = min(r0 + lr, M-1);
  int qrow = usemap ? qmapf(uh, qr) : qr;

  __shared__ u16 Klds[64*128];      // [key][d-slot], source pre-swizzled
  __shared__ u16 Vlds[128*64];      // [d][key-slot], source pre-swizzled
  __shared__ u16 plsm[4][16*80];

  s16x8 qf[4];
#pragma unroll
  for (int kd=0; kd<4; ++kd) qf[kd] = ld8(q + (size_t)qrow*qld + kd*32 + lk*8);
  f32x4 oacc[8];
#pragma unroll
  for (int i=0;i<8;i++) oacc[i] = (f32x4){0,0,0,0};
  float mr[4] = {-1e30f,-1e30f,-1e30f,-1e30f};
  float ls[4] = {0,0,0,0};

  int t0 = (tiles_total * c) / nchunks;
  int t1 = (tiles_total * (c+1)) / nchunks;
  for (int kt=t0; kt<t1; ++kt){
    int kb = kt*64;
    // ---- async staging: K 64x128 + Vt 128x64, linear LDS dest, swizzled src
#pragma unroll
    for (int it=0; it<4; ++it){
      int ch = it*256 + tid;
      int key = ch >> 4, seg = ch & 15;
      int kc = min(kb + key, Nk-1);
      int kg = usemap ? qmapf(uh, kc) : kc;
      gload16(kk + (size_t)kg*qld + (((seg ^ (key&7))&15)<<3), Klds + ch*8);
      int dd = ch >> 3, sg = ch & 7;
      gload16(vt + (size_t)dd*vt_ld + kb + ((sg ^ (dd&7))<<3), Vlds + ch*8);
    }
    asm volatile("s_waitcnt vmcnt(0)" ::: "memory");
    __syncthreads();
    f32x4 s[4];
#pragma unroll
    for (int n=0;n<4;n++) s[n] = (f32x4){0,0,0,0};
    __builtin_amdgcn_s_setprio(1);
#pragma unroll
    for (int n=0;n<4;n++){
      int key = n*16 + lr;
#pragma unroll
      for (int kd=0; kd<4; ++kd){
        s16x8 kf = *(const s16x8*)(Klds + key*128 + ((kd*32 + lk*8) ^ ((key&7)<<3)));
        MFMA(s[n], qf[kd], kf);
      }
    }
    __builtin_amdgcn_s_setprio(0);
#pragma unroll
    for (int n=0;n<4;n++){
      bool valid = (kb + n*16 + lr) < Nk;
#pragma unroll
      for (int r=0;r<4;r++){
        float v2 = s[n][r]*scale;
        s[n][r] = valid ? v2 : -1e30f;
      }
    }
    float mx[4];
#pragma unroll
    for (int r=0;r<4;r++) mx[r] = fmaxf(fmaxf(s[0][r],s[1][r]), fmaxf(s[2][r],s[3][r]));
#pragma unroll
    for (int off=1; off<16; off<<=1){
#pragma unroll
      for (int r=0;r<4;r++) mx[r] = fmaxf(mx[r], __shfl_xor(mx[r], off, 64));
    }
    float al[4], rs[4];
#pragma unroll
    for (int r=0;r<4;r++){
      float mnew = fmaxf(mr[r], mx[r]);
      al[r] = __expf(mr[r]-mnew);
      mr[r] = mnew;
      rs[r] = 0.f;
    }
#pragma unroll
    for (int n=0;n<4;n++){
#pragma unroll
      for (int r=0;r<4;r++){
        float p = __expf(s[n][r]-mr[r]);
        rs[r] += p;
        plsm[w][(lk*4+r)*80 + n*16 + lr] = f2b(p);
      }
    }
#pragma unroll
    for (int off=1; off<16; off<<=1){
#pragma unroll
      for (int r=0;r<4;r++) rs[r] += __shfl_xor(rs[r], off, 64);
    }
#pragma unroll
    for (int r=0;r<4;r++) ls[r] = ls[r]*al[r] + rs[r];
#pragma unroll
    for (int cf=0; cf<8; cf++){
#pragma unroll
      for (int r=0;r<4;r++) oacc[cf][r] *= al[r];
    }
    __syncthreads();
    __builtin_amdgcn_s_setprio(1);
#pragma unroll
    for (int kd2=0; kd2<2; ++kd2){
      s16x8 pa = *(const s16x8*)(plsm[w] + lr*80 + kd2*32 + lk*8);
#pragma unroll
      for (int cf=0; cf<8; ++cf){
        int dd = cf*16 + lr;
        s16x8 vb = *(const s16x8*)(Vlds + dd*64 + ((kd2*32 + lk*8) ^ ((dd&7)<<3)));
        MFMA(oacc[cf], pa, vb);
      }
    }
    __builtin_amdgcn_s_setprio(0);
    __syncthreads();
  }
  size_t pbase = ((size_t)u*nchunks + c)*M;
#pragma unroll
  for (int cf=0; cf<8; ++cf){
#pragma unroll
    for (int r=0;r<4;r++){
      int row = r0 + lk*4 + r;
      if (row < M) po[(pbase + row)*128 + cf*16 + lr] = oacc[cf][r];
    }
  }
  if (lr == 0){
#pragma unroll
    for (int r=0;r<4;r++){
      int row = r0 + lk*4 + r;
      if (row < M){ pm[pbase + row] = mr[r]; pl[pbase + row] = ls[r]; }
    }
  }
}

// ---------------- flash combine: merge K-chunks, normalize ------------------
__global__ __launch_bounds__(256) void fcomb_kernel(
    const float* __restrict__ po, const float* __restrict__ pm, const float* __restrict__ pl,
    u16* __restrict__ out_bf, float* __restrict__ out_f,
    int rows, int nunits, int nchunks, long o_hi_stride)
{
  int w = threadIdx.x >> 6, lane = threadIdx.x & 63;
  int gid = blockIdx.x*4 + w;
  if (gid >= nunits*rows) return;
  int u = gid / rows, row = gid - u*rows;
  size_t pb = (size_t)u*nchunks*rows + row;
  float m = -1e30f;
  for (int c=0;c<nchunks;c++) m = fmaxf(m, pm[pb + (size_t)c*rows]);
  float L = 0.f, o0 = 0.f, o1 = 0.f;
  for (int c=0;c<nchunks;c++){
    float wgt = __expf(pm[pb + (size_t)c*rows] - m);
    L += wgt * pl[pb + (size_t)c*rows];
    const float* op = po + (pb + (size_t)c*rows)*128;
    o0 += wgt * op[lane*2];
    o1 += wgt * op[lane*2+1];
  }
  float inv = 1.f/L;
  int uh = u>>2, ul = u&3;
  size_t idx = (size_t)uh*o_hi_stride + (size_t)row*512 + ul*128 + lane*2;
  if (out_bf){ out_bf[idx] = f2b(o0*inv); out_bf[idx+1] = f2b(o1*inv); }
  else       { out_f[idx]  = o0*inv;      out_f[idx+1]  = o1*inv; }
}

// ---------------- LayerNorm: one wave per 512-wide row ----------------------
__global__ __launch_bounds__(256) void ln_kernel(
    const u16* __restrict__ inb,
    const u16* __restrict__ gw, const u16* __restrict__ bw,
    u16* __restrict__ out, int rows)
{
  int w = threadIdx.x >> 6, lane = threadIdx.x & 63;
  int row = blockIdx.x*4 + w;
  if (row >= rows) return;
  float x[8];
  s16x8 v = ld8(inb + (size_t)row*512 + lane*8);
#pragma unroll
  for (int j=0;j<8;j++) x[j] = b2f((u16)v[j]);
  float s = 0.f;
#pragma unroll
  for (int j=0;j<8;j++) s += x[j];
#pragma unroll
  for (int off=1; off<64; off<<=1) s += __shfl_xor(s, off, 64);
  float mean = s*(1.f/512.f);
  float vs = 0.f;
#pragma unroll
  for (int j=0;j<8;j++){ float d = x[j]-mean; vs += d*d; }
#pragma unroll
  for (int off=1; off<64; off<<=1) vs += __shfl_xor(vs, off, 64);
  float rstd = 1.f/sqrtf(vs*(1.f/512.f) + 1e-5f);
#pragma unroll
  for (int j=0;j<8;j++){
    int c = lane*8+j;
    float y = (x[j]-mean)*rstd*b2f(gw[c]) + b2f(bw[c]);
    out[(size_t)row*512 + c] = f2b(y);
  }
}

// ---------------- mem_fin[0] = x verbatim (dtype-branched) ------------------
__global__ __launch_bounds__(256) void copy_out_kernel(
    const u16* __restrict__ s16, const float* __restrict__ s32,
    const int* __restrict__ flag, u16* __restrict__ dbf, float* __restrict__ df, int n8)
{
  int i = blockIdx.x*256 + threadIdx.x;
  if (i >= n8) return;
  if (*flag){
    ((f32x4*)df)[i*2]   = ((const f32x4*)s32)[i*2];
    ((f32x4*)df)[i*2+1] = ((const f32x4*)s32)[i*2+1];
  } else {
    ((s16x8*)dbf)[i] = ((const s16x8*)s16)[i];
  }
}

// ---------------------------------------------------------------------------
extern "C" void kernel_launch(void* const* d_in, const int* in_sizes, int n_in,
                              void* d_out, int out_size, void* d_ws, size_t ws_size,
                              hipStream_t stream)
{
  u16* outp16 = (u16*)d_out;
  float* outp32 = (float*)d_out;

  char* wsb = (char*)d_ws;
  size_t off = 0;
  auto alloc = [&](size_t bytes)->void*{
    void* p = wsb + off; off += (bytes + 255) & ~(size_t)255; return p; };

  int* flagp = (int*)alloc(256);

  static const int din_idx[15] = {0, 2,3, 5,7,9,11, 12,13, 15,17, 18,19, 21,23};
  static const int din_n[15]   = {829440, 512,512, 512,512,512,512, 512,512,
                                  2048,512, 512,512, 2048,512};
  NormArgs na;
  u16* cptr[15];
  int total = 0;
  for (int i=0;i<15;i++){ na.src[i] = d_in[din_idx[i]]; na.cumblk[i] = total/512; total += din_n[i]; }
  na.cumblk[15] = total/512;
  u16* canon = (u16*)alloc((size_t)total*2);
  { int c = 0; for (int i=0;i<15;i++){ cptr[i] = canon + c; c += din_n[i]; } }
  const u16 *cx=cptr[0], *cg1=cptr[1], *cb1=cptr[2],
            *cbq=cptr[3], *cbk=cptr[4], *cbv=cptr[5], *cbo=cptr[6],
            *cg2=cptr[7], *cb2=cptr[8], *cfb1s=cptr[9], *cfb2s=cptr[10],
            *ctg2=cptr[11], *ctb2=cptr[12], *cfb1t=cptr[13], *cfb2t=cptr[14];

  u16* wqkvT = (u16*)alloc((size_t)1536*512*2);
  u16* woT  = (u16*)alloc(512*512*2);
  u16* w1sT = (u16*)alloc(2048*512*2);
  u16* w2sT = (u16*)alloc((size_t)512*2048*2);
  u16* w1tT = (u16*)alloc(2048*512*2);
  u16* w2tT = (u16*)alloc((size_t)512*2048*2);
  u16* xn   = (u16*)alloc(1620*512*2);
  u16* qkv  = (u16*)alloc((size_t)1620*1536*2);
  u16* vT   = (u16*)alloc((size_t)512*1664*2);
  u16* attn = (u16*)alloc(1620*512*2);
  float* xu = (float*)alloc((size_t)1620*512*4);
  u16* yb   = (u16*)alloc(1620*512*2);
  u16* hh   = (u16*)alloc((size_t)1620*2048*2);
  u16* xgT  = (u16*)alloc((size_t)4*512*448*2);
  float* ot = (float*)alloc((size_t)4*405*512*4);
  float* xut= (float*)alloc((size_t)1620*512*4);
  u16* yt   = (u16*)alloc(1620*512*2);
  u16* ht   = (u16*)alloc((size_t)1620*2048*2);
  float* po = (float*)alloc((size_t)4*4*1620*128*4);
  float* pm = (float*)alloc((size_t)4*4*1620*4);
  float* pl = (float*)alloc((size_t)4*4*1620*4);

  const float scale = 0.08838834764831843f;   // 1/sqrt(128)
  dim3 tb(32,8);

  detect_kernel<<<dim3(1), dim3(64), 0, stream>>>((const u16*)d_in[0], flagp);
  norm_kernel<<<dim3(total/512), dim3(64), 0, stream>>>(na, flagp, canon);

  // batched weight transposes straight from d_in (dtype-aware)
  {
    TJobs J;
    const void* srcs[8] = {d_in[4], d_in[6], d_in[8], d_in[10],
                           d_in[14], d_in[16], d_in[20], d_in[22]};
    u16* dsts[8] = {wqkvT, wqkvT + (size_t)512*512, wqkvT + (size_t)1024*512,
                    woT, w1sT, w2sT, w1tT, w2tT};
    int Rs[8]   = {512,512,512,512, 512,2048, 512,2048};
    int Cs[8]   = {512,512,512,512, 2048,512, 2048,512};
    int t2 = 0;
    J.cum[0] = 0;
    for (int i=0;i<8;i++){
      J.src[i]=srcs[i]; J.dst[i]=dsts[i]; J.R[i]=Rs[i]; J.C32[i]=Cs[i]/32;
      J.srcld[i]=Cs[i]; J.dstld[i]=Rs[i]; J.gmap[i]=-1;
      t2 += (Rs[i]/32)*(Cs[i]/32);
      J.cum[i+1]=t2;
    }
    trans_kernel<<<dim3(t2), tb, 0, stream>>>(J, flagp);
  }

  // xgT: mapped transpose straight from canon x (replaces gather+transpose)
  {
    TJobs J;
    int per = (448/32)*(512/32);
    for (int g=0; g<4; ++g){
      J.src[g]=cx; J.dst[g]=xgT + (size_t)g*512*448;
      J.R[g]=405; J.C32[g]=512/32; J.srcld[g]=512; J.dstld[g]=448; J.gmap[g]=g;
    }
    J.cum[0]=0;
    for (int i=1;i<9;i++) J.cum[i] = (i<=4) ? per*i : per*4;
    trans_kernel<<<dim3(per*4), tb, 0, stream>>>(J, nullptr);
  }
  // temporal flash early (depends only on x): mapped Q/K from cx
  flash4_kernel<<<dim3(7,16,4), dim3(256), 0, stream>>>(cx, cx, xgT, po, pm, pl,
      405, 405, 512, 7, 4, 0L, (long)(512*448), 448, scale, 1);
  fcomb_kernel<<<dim3(1620), dim3(256), 0, stream>>>(po, pm, pl, nullptr, ot,
      405, 16, 4, (long)(405*512));

  // spatial block
  ln_kernel<<<dim3(405), dim3(256), 0, stream>>>(cx, cg1, cb1, xn, 1620);
  gemm_s_kernel<<<dim3(24,26,1), dim3(256), 0, stream>>>(xn, wqkvT, cbq, cbk, cbv,
      1620,1536,512, 1, nullptr, nullptr,nullptr, qkv, nullptr, nullptr,nullptr,nullptr, 0);
  {
    TJobs J;
    J.src[0]=qkv+1024; J.dst[0]=vT; J.R[0]=1620; J.C32[0]=512/32;
    J.srcld[0]=1536; J.dstld[0]=1664; J.gmap[0]=-1;
    int t2 = (1664/32)*(512/32);
    J.cum[0]=0; for (int i=1;i<9;i++) J.cum[i]=t2;
    trans_kernel<<<dim3(t2), tb, 0, stream>>>(J, nullptr);
  }
  flash4_kernel<<<dim3(26,4,4), dim3(256), 0, stream>>>(qkv, qkv+512, vT, po, pm, pl,
      1620, 1620, 1536, 26, 4, 0L, 0L, 1664, scale, 0);
  fcomb_kernel<<<dim3(1620), dim3(256), 0, stream>>>(po, pm, pl, attn, nullptr,
      1620, 4, 4, 0L);
  gemm_s_kernel<<<dim3(8,26,2), dim3(256), 0, stream>>>(attn, woT, nullptr,nullptr,nullptr,
      1620,512,512, 2, po, nullptr,nullptr, nullptr,nullptr, nullptr,nullptr,nullptr, 0);
  comb_ln_kernel<<<dim3(405), dim3(256), 0, stream>>>(po, 2, cbo, 1620, cx, xu,
      cg2, cb2, yb);
  gemm_s_kernel<<<dim3(32,26,1), dim3(256), 0, stream>>>(yb, w1sT, cfb1s, nullptr,nullptr,
      1620,2048,512, 1, nullptr, nullptr,nullptr, hh, nullptr, nullptr,nullptr,nullptr, 1);
  gemm_s_kernel<<<dim3(8,26,2), dim3(256), 0, stream>>>(hh, w2sT, nullptr,nullptr,nullptr,
      1620,512,2048, 2, po, nullptr,nullptr, nullptr,nullptr, nullptr,nullptr,nullptr, 0);
  // fused: FFN2s combine + mem_fin[1] write + temporal combine + LN -> yt
  ffn2_comb_ln_kernel<<<dim3(405), dim3(256), 0, stream>>>(po, cfb2s, 1620,
      xu, ot, flagp, outp16 + 1658880, outp32 + 1658880, xut, ctg2, ctb2, yt);

  // temporal FFN
  gemm_s_kernel<<<dim3(32,26,1), dim3(256), 0, stream>>>(yt, w1tT, cfb1t, nullptr,nullptr,
      1620,2048,512, 1, nullptr, nullptr,nullptr, ht, nullptr, nullptr,nullptr,nullptr, 1);
  gemm_s_kernel<<<dim3(8,26,2), dim3(256), 0, stream>>>(ht, w2tT, nullptr,nullptr,nullptr,
      1620,512,2048, 2, po, nullptr,nullptr, nullptr,nullptr, nullptr,nullptr,nullptr, 0);
  gemm_comb_kernel<<<dim3(405), dim3(256), 0, stream>>>(po, 2, cfb2t, 1620, 0,
      nullptr, xut, nullptr, nullptr, flagp, outp16, outp32);

  // mem_fin[0] = x verbatim
  copy_out_kernel<<<dim3(405), dim3(256), 0, stream>>>((const u16*)d_in[0],
      (const float*)d_in[0], flagp, outp16 + 829440, outp32 + 829440, 103680);
}